// Round 3
// baseline (3435.748 us; speedup 1.0000x reference)
//
#include <hip/hip_runtime.h>
#include <cstdint>
#include <cstddef>

typedef unsigned short u16;
typedef __attribute__((ext_vector_type(8))) short short8;
typedef __attribute__((ext_vector_type(4))) float f32x4;

// B=512, T=64, D=16, H=1024 ; 4H=4096
#define NB 512
#define NT 64
#define ND 16
#define NH 1024
#define LDSW 16384  // u16 per pipeline buffer: A 128x64 + B 128x64

__device__ __forceinline__ u16 f2bf(float x) {
  union { float f; unsigned u; } v; v.f = x;
  unsigned r = v.u + 0x7fffu + ((v.u >> 16) & 1u);
  return (u16)(r >> 16);
}
__device__ __forceinline__ float bf2f(u16 u) {
  union { float f; unsigned u; } v; v.u = ((unsigned)u) << 16;
  return v.f;
}
__device__ __forceinline__ float sigf(float x) { return 1.f / (1.f + __expf(-x)); }

__device__ __forceinline__ void glds16(const void* g, void* l) {
  __builtin_amdgcn_global_load_lds((const __attribute__((address_space(1))) void*)g,
                                   (__attribute__((address_space(3))) void*)l, 16, 0, 0);
}

// XOR swizzle: 16B-slot ^= (row & 7). Bijective within each 64-col (8-slot) chunk.
__device__ __forceinline__ int swz(int row, int col) {
  return ((((col >> 3) ^ (row & 7)) << 3) | (col & 7));
}

// n' = (h/16)*64 + gate*16 + (h%16)  ->  orig row = gate*1024 + h
__device__ __forceinline__ int inv_np(int np) {
  int hb = np >> 6, g = (np >> 4) & 3, hlo = np & 15;
  return g * 1024 + hb * 16 + hlo;
}

// ---------------- prep: big weight matrices (K=1024) -> bf16 reordered + swizzled ----------------
__global__ void k_prep_big(const float* s0, const float* s1, const float* s2,
                           const float* s3, const float* s4, const float* s5, u16* dst) {
  for (unsigned q = blockIdx.x * 256 + threadIdx.x; q < (6u << 20); q += gridDim.x * 256) {
    int mat = q >> 20;
    int rem = q & ((1 << 20) - 1);
    int np = rem >> 8;            // 0..4095
    int k = (rem & 255) * 4;      // 0..1020
    int row = inv_np(np);
    const float* s = mat == 0 ? s0 : mat == 1 ? s1 : mat == 2 ? s2 : mat == 3 ? s3 : mat == 4 ? s4 : s5;
    float4 v = *(const float4*)(s + (size_t)row * NH + k);
    u16* d = dst + (size_t)mat * 4194304 + (size_t)np * NH + swz(np, k);
    d[0] = f2bf(v.x); d[1] = f2bf(v.y); d[2] = f2bf(v.z); d[3] = f2bf(v.w);
  }
}

// ---------------- prep: Wih0 padded to K=64 (swizzled), combined biases, out_W bf16 ----------------
__global__ void k_prep_small(const float* fwih0, const float* bwih0,
                             const float* fbi0, const float* fbh0, const float* fbi1, const float* fbh1,
                             const float* bbi0, const float* bbh0, const float* bbi1, const float* bbh1,
                             const float* outW,
                             u16* wih0p, float* biasb, u16* owbf) {
  int idx = blockIdx.x * 256 + threadIdx.x;
  if (idx < 524288) {
    int dir = idx >> 18;
    int r = idx & 262143;
    int np = r >> 6, d = r & 63;
    int row = inv_np(np);
    const float* s = dir ? bwih0 : fwih0;
    float v = (d < 16) ? s[row * 16 + d] : 0.f;
    wih0p[(size_t)dir * 262144 + (size_t)np * 64 + swz(np, d)] = f2bf(v);
  } else if (idx < 524288 + 16384) {
    int j = idx - 524288;
    int which = j >> 12;  // 0 fw-l0, 1 fw-l1, 2 bw-l0, 3 bw-l1
    int np = j & 4095;
    int row = inv_np(np);
    const float* bi = which == 0 ? fbi0 : which == 1 ? fbi1 : which == 2 ? bbi0 : bbi1;
    const float* bh = which == 0 ? fbh0 : which == 1 ? fbh1 : which == 2 ? bbh0 : bbh1;
    biasb[which * 4096 + np] = bi[row] + bh[row];
  } else if (idx < 524288 + 16384 + 16384) {
    int j = idx - 524288 - 16384;   // d*1024 + h
    owbf[j] = f2bf(outW[j]);
  }
}

// ---------------- init: pre-loop layer-1 cell from biases; zero layer-0 state ----------------
__global__ void k_init(const float* fbi1, const float* fbh1, const float* bbi1, const float* bbh1,
                       float* c0, float* c1, u16* h0bf, u16* h1bf) {
  int idx = blockIdx.x * 256 + threadIdx.x;  // 2*512*1024 exact
  int dir = idx >> 19;
  int rem = idx & ((1 << 19) - 1);
  int b = rem >> 10, h = rem & 1023;
  const float* bi = dir ? bbi1 : fbi1;
  const float* bh = dir ? bbh1 : fbh1;
  float gi = bi[h] + bh[h];
  float gg = bi[2048 + h] + bh[2048 + h];
  float go = bi[3072 + h] + bh[3072 + h];
  float c = sigf(gi) * tanhf(gg);
  float hv = sigf(go) * tanhf(c);
  size_t o = (size_t)dir * 524288 + rem;
  c1[o] = c;
  h1bf[(size_t)(dir * 2) * 524288 + (size_t)b * NH + swz(b, h)] = f2bf(hv);  // buf 0, swizzled
  c0[o] = 0.f;
  h0bf[(size_t)(dir * 2) * 524288 + rem] = 0;  // zeros: layout-independent
}

// ---------------- t=0 cc seed: partial[dir][0][b][d] = h1_init @ out_W^T (pre-mask) ----------------
__global__ __launch_bounds__(256) void k_cc0(const u16* h1f, const u16* h1b,
                                             const float* outW, float* partial) {
  int dir = blockIdx.y;
  int w = threadIdx.x >> 6, lane = threadIdx.x & 63;
  int b = blockIdx.x * 4 + w;
  const u16* hb = dir ? h1b : h1f;
  int key = b & 7;
  int s0 = lane * 2, s1 = lane * 2 + 1;
  short8 ha = *(const short8*)(hb + (size_t)b * NH + (s0 ^ key) * 8);
  short8 hc = *(const short8*)(hb + (size_t)b * NH + (s1 ^ key) * 8);
  float hf[16];
#pragma unroll
  for (int j = 0; j < 8; ++j) { hf[j] = bf2f((u16)ha[j]); hf[8 + j] = bf2f((u16)hc[j]); }
  float sums[16];
#pragma unroll
  for (int d = 0; d < 16; ++d) {
    const float* wr = outW + (size_t)d * NH + lane * 16;
    float s = 0.f;
#pragma unroll
    for (int j = 0; j < 16; ++j) s += hf[j] * wr[j];
#pragma unroll
    for (int off = 32; off; off >>= 1) s += __shfl_xor(s, off);
    sums[d] = s;
  }
  if (lane == 0) {
    float* dst = partial + (size_t)dir * 262144 + (size_t)b * 16;
#pragma unroll
    for (int d = 0; d < 16; ++d) dst[d] = sums[d];
  }
}

// ---------------- fused GEMM + LSTM cell, 128x128 tile, depth-3 pipeline ----------------
struct GArgs {
  const u16* A0[2]; const u16* W0[2];
  const u16* A1[2]; const u16* W1[2];
  const u16* Wcc[2];
  const float* bias[2];
  float* c_st[2];
  u16* h_out[2];
  const float* ccpart_in;   // g0: reduce these + mask -> chunk0 A tile (in LDS)
  float* ccpart_out;        // g1: write h1@outW^T partials
  const float* values; const float* masks; const float* outb;
  const u16* owbf;
  int nk; int nk0; int ccmode; int t;
};

__global__ __launch_bounds__(256) void k_gemm_cell(GArgs ar) {
  extern __shared__ u16 SM[];   // 4*LDSW pipeline + 2048 u16 transpose scratch
  const int dir = blockIdx.z;
  const int tid = threadIdx.x, w = tid >> 6, lane = tid & 63;
  const int m0 = blockIdx.y * 128, n0 = blockIdx.x * 128;
  const int nk = ar.nk, nk0 = ar.nk0, ccmode = ar.ccmode;

  const u16* A0 = ar.A0[dir]; const u16* W0 = ar.W0[dir];
  const u16* A1 = ar.A1[dir]; const u16* W1 = ar.W1[dir];
  const u16* Wcc = ar.Wcc[dir];

  f32x4 acc[4][4];
#pragma unroll
  for (int i = 0; i < 4; ++i)
#pragma unroll
    for (int j = 0; j < 4; ++j) acc[i][j] = f32x4{0.f, 0.f, 0.f, 0.f};

  const int srow = lane >> 3;        // staging row within 8-row group
  const int scol = (lane & 7) * 8;   // staging col (u16)
  const int wm = w >> 1, wn = w & 1;
  const int fr = lane & 15, fq = lane >> 4;
  const int key = fr & 7;

  int aoff[4][2], boff[4][2];
#pragma unroll
  for (int mi = 0; mi < 4; ++mi) {
    int row = wm * 64 + mi * 16 + fr;
#pragma unroll
    for (int kk = 0; kk < 2; ++kk) aoff[mi][kk] = row * 64 + ((fq + kk * 4) ^ key) * 8;
  }
#pragma unroll
  for (int ni = 0; ni < 4; ++ni) {
    int row = wn * 64 + ni * 16 + fr;
#pragma unroll
    for (int kk = 0; kk < 2; ++kk) boff[ni][kk] = 8192 + row * 64 + ((fq + kk * 4) ^ key) * 8;
  }

  // ---- prologue (g0): reduce cc partials, apply mask, write chunk-0 A tile into LDS ----
  if (ccmode) {
    const int rl = tid >> 1;            // local row 0..127
    const int dh = (tid & 1) * 8;       // d 0..7 or 8..15
    const int grow = m0 + rl;           // batch row
    float ps[8] = {0.f, 0.f, 0.f, 0.f, 0.f, 0.f, 0.f, 0.f};
    const float* pp = ar.ccpart_in + (size_t)dir * 262144 + (size_t)grow * 16 + dh;
    for (int nb = 0; nb < 32; ++nb) {
      float4 v0 = *(const float4*)(pp + (size_t)nb * 8192);
      float4 v1 = *(const float4*)(pp + (size_t)nb * 8192 + 4);
      ps[0] += v0.x; ps[1] += v0.y; ps[2] += v0.z; ps[3] += v0.w;
      ps[4] += v1.x; ps[5] += v1.y; ps[6] += v1.z; ps[7] += v1.w;
    }
    int tt = dir ? (NT - 1 - ar.t) : ar.t;
    const float* xv = ar.values + ((size_t)grow * NT + tt) * ND + dh;
    const float* mv = ar.masks + ((size_t)grow * NT + tt) * ND + dh;
    float4 x0 = *(const float4*)xv, x1 = *(const float4*)(xv + 4);
    float4 mm0 = *(const float4*)mv, mm1 = *(const float4*)(mv + 4);
    float4 ob0 = *(const float4*)(ar.outb + dh), ob1 = *(const float4*)(ar.outb + dh + 4);
    float xs[8] = {x0.x, x0.y, x0.z, x0.w, x1.x, x1.y, x1.z, x1.w};
    float ms[8] = {mm0.x, mm0.y, mm0.z, mm0.w, mm1.x, mm1.y, mm1.z, mm1.w};
    float obs[8] = {ob0.x, ob0.y, ob0.z, ob0.w, ob1.x, ob1.y, ob1.z, ob1.w};
    short8 cc;
#pragma unroll
    for (int j = 0; j < 8; ++j)
      cc[j] = (short)f2bf((1.f - ms[j]) * (ps[j] + obs[j]) + ms[j] * xs[j]);
    int s = tid & 1, k2 = rl & 7;
    *(short8*)(SM + rl * 64 + (s ^ k2) * 8) = cc;
    short8 z = {0, 0, 0, 0, 0, 0, 0, 0};
    *(short8*)(SM + rl * 64 + (((s + 2) & 7) ^ k2) * 8) = z;
    *(short8*)(SM + rl * 64 + (((s + 4) & 7) ^ k2) * 8) = z;
    *(short8*)(SM + rl * 64 + (((s + 6) & 7) ^ k2) * 8) = z;
    asm volatile("s_waitcnt vmcnt(0) lgkmcnt(0)" ::: "memory");
    __builtin_amdgcn_sched_barrier(0);
  }

  auto stage = [&](int c) {
    int buf = c & 3;
    u16* lb = SM + buf * LDSW;
    if (ccmode && c == 0) {
#pragma unroll
      for (int k = 0; k < 4; ++k)
        glds16(Wcc + (size_t)(n0 + w * 32 + k * 8 + srow) * 64 + scol,
               lb + 8192 + (w * 32 + k * 8) * 64);
      return;  // 4 loads/wave (vs 8) — first vmcnt(24) covers the deficit
    }
    int ci = ccmode ? c - 1 : c;
    const u16* pa; const u16* pw;
    if (ci < nk0) { pa = A0 + (size_t)ci * 64; pw = W0 + (size_t)ci * 64; }
    else { pa = A1 + (size_t)(ci - nk0) * 64; pw = W1 + (size_t)(ci - nk0) * 64; }
#pragma unroll
    for (int k = 0; k < 4; ++k)
      glds16(pa + (size_t)(m0 + w * 32 + k * 8 + srow) * NH + scol,
             lb + (w * 32 + k * 8) * 64);
#pragma unroll
    for (int k = 0; k < 4; ++k)
      glds16(pw + (size_t)(n0 + w * 32 + k * 8 + srow) * NH + scol,
             lb + 8192 + (w * 32 + k * 8) * 64);
  };

  stage(0); stage(1); stage(2);
  for (int t = 0; t < nk; ++t) {
    if (t + 3 < nk) {
      stage(t + 3);
      asm volatile("s_waitcnt vmcnt(24)" ::: "memory");
    } else {
      int rem = nk - 1 - t;
      if (rem == 2)      asm volatile("s_waitcnt vmcnt(16)" ::: "memory");
      else if (rem == 1) asm volatile("s_waitcnt vmcnt(8)" ::: "memory");
      else               asm volatile("s_waitcnt vmcnt(0)" ::: "memory");
    }
    __builtin_amdgcn_s_barrier();
    __builtin_amdgcn_sched_barrier(0);

    const u16* base = SM + (t & 3) * LDSW;
    short8 af[4][2], bfr[4][2];
#pragma unroll
    for (int kk = 0; kk < 2; ++kk) {
#pragma unroll
      for (int mi = 0; mi < 4; ++mi) af[mi][kk] = *(const short8*)(base + aoff[mi][kk]);
#pragma unroll
      for (int ni = 0; ni < 4; ++ni) bfr[ni][kk] = *(const short8*)(base + boff[ni][kk]);
    }
#pragma unroll
    for (int kk = 0; kk < 2; ++kk)
#pragma unroll
      for (int mi = 0; mi < 4; ++mi)
#pragma unroll
        for (int ni = 0; ni < 4; ++ni)
          acc[mi][ni] = __builtin_amdgcn_mfma_f32_16x16x32_bf16(af[mi][kk], bfr[ni][kk], acc[mi][ni], 0, 0, 0);

    __builtin_amdgcn_sched_barrier(0);
    __builtin_amdgcn_s_barrier();
  }

  // ---- epilogue: bias + LSTM cell ----
  const float* bias = ar.bias[dir];
  float* cs = ar.c_st[dir];
  u16* ho = ar.h_out[dir];
  const int hb4 = (n0 + wn * 64) >> 2;
  const int hg = hb4 + fr;
  const float b0 = bias[n0 + wn * 64 + fr];
  const float b1 = bias[n0 + wn * 64 + 16 + fr];
  const float b2 = bias[n0 + wn * 64 + 32 + fr];
  const float b3 = bias[n0 + wn * 64 + 48 + fr];
  float hsv[4][4];
#pragma unroll
  for (int mi = 0; mi < 4; ++mi)
#pragma unroll
    for (int r = 0; r < 4; ++r) {
      int row = m0 + wm * 64 + mi * 16 + fq * 4 + r;
      size_t sidx = (size_t)row * NH + hg;
      float iv = acc[mi][0][r] + b0;
      float fv = acc[mi][1][r] + b1;
      float gv = acc[mi][2][r] + b2;
      float ov = acc[mi][3][r] + b3;
      float cp = cs[sidx];
      float c2 = sigf(fv) * cp + sigf(iv) * tanhf(gv);
      float hvv = sigf(ov) * tanhf(c2);
      cs[sidx] = c2;
      ho[(size_t)row * NH + swz(row, hg)] = f2bf(hvv);
      hsv[mi][r] = hvv;
    }

  // ---- g1 extra epilogue: partial cc = h1_block @ outW^T via transpose-mfma ----
  if (ar.ccpart_out) {
    u16* ts = SM + 4 * LDSW + w * 512;  // per-wave 16x32 u16 scratch
    // zero pad cols 16..31 (once)
    *(short4*)(ts + (lane >> 2) * 32 + 16 + (lane & 3) * 4) = short4{0, 0, 0, 0};
    short8 afr = {0, 0, 0, 0, 0, 0, 0, 0};
    if (fq < 2) afr = *(const short8*)(ar.owbf + (size_t)fr * NH + hb4 + fq * 8);
#pragma unroll
    for (int mi = 0; mi < 4; ++mi) {
#pragma unroll
      for (int r = 0; r < 4; ++r)
        *(ts + (fq * 4 + r) * 32 + fr) = f2bf(hsv[mi][r]);
      asm volatile("s_waitcnt lgkmcnt(0)" ::: "memory");
      __builtin_amdgcn_sched_barrier(0);
      short8 bfr2 = *(const short8*)(ts + fr * 32 + fq * 8);
      f32x4 pz = {0.f, 0.f, 0.f, 0.f};
      pz = __builtin_amdgcn_mfma_f32_16x16x32_bf16(afr, bfr2, pz, 0, 0, 0);
      int row = m0 + wm * 64 + mi * 16 + fr;
      float4 st = {pz[0], pz[1], pz[2], pz[3]};
      *(float4*)(ar.ccpart_out + ((size_t)(dir * 32 + blockIdx.x) * 512 + row) * 16 + fq * 4) = st;
      asm volatile("s_waitcnt lgkmcnt(0)" ::: "memory");
      __builtin_amdgcn_sched_barrier(0);
    }
  }
}

// ---------------- final outputs ----------------
__global__ void k_final(const u16* hf1, const u16* hb1, const float* values,
                        const float* masks, float* out) {
  int idx = blockIdx.x * 256 + threadIdx.x;  // 524288 exact
  int b = idx >> 10, j = idx & 1023;
  float hf = bf2f(hf1[(size_t)b * NH + swz(b, j)]);
  int jr = NH - 1 - j;
  float hb = bf2f(hb1[(size_t)b * NH + swz(b, jr)]);
  float hv = 0.5f * (hf + hb);
  float m = masks[idx];
  out[idx] = hv;
  out[524288 + idx] = hv;
  out[1048576 + idx] = hv * (1.f - m) + values[idx] * m;
}

extern "C" void kernel_launch(void* const* d_in, const int* in_sizes, int n_in,
                              void* d_out, int out_size, void* d_ws, size_t ws_size,
                              hipStream_t stream) {
  const float* values  = (const float*)d_in[0];
  const float* masks   = (const float*)d_in[1];
  const float* fw_Wih0 = (const float*)d_in[2];
  const float* fw_Whh0 = (const float*)d_in[3];
  const float* fw_bih0 = (const float*)d_in[4];
  const float* fw_bhh0 = (const float*)d_in[5];
  const float* fw_Wih1 = (const float*)d_in[6];
  const float* fw_Whh1 = (const float*)d_in[7];
  const float* fw_bih1 = (const float*)d_in[8];
  const float* fw_bhh1 = (const float*)d_in[9];
  const float* bw_Wih0 = (const float*)d_in[10];
  const float* bw_Whh0 = (const float*)d_in[11];
  const float* bw_bih0 = (const float*)d_in[12];
  const float* bw_bhh0 = (const float*)d_in[13];
  const float* bw_Wih1 = (const float*)d_in[14];
  const float* bw_Whh1 = (const float*)d_in[15];
  const float* bw_bih1 = (const float*)d_in[16];
  const float* bw_bhh1 = (const float*)d_in[17];
  const float* out_W   = (const float*)d_in[18];
  const float* out_b   = (const float*)d_in[19];

  char* ws = (char*)d_ws;
  u16* wbig    = (u16*)ws;                    // 6 x 4M u16
  u16* wih0p   = (u16*)(ws + 50331648);       // 2 x 4096x64
  float* biasb = (float*)(ws + 51380224);     // 4 x 4096
  u16* owbf    = (u16*)(ws + 51445760);       // 16x1024 bf16
  float* c0    = (float*)(ws + 51478528);     // 2 x 512x1024 f32
  float* c1    = (float*)(ws + 55672832);
  u16* h0bf    = (u16*)(ws + 59867136);       // [dir][pp] x 512x1024 bf16 swizzled
  u16* h1bf    = (u16*)(ws + 64061440);
  float* partial = (float*)(ws + 68255744);   // [dir][32][512][16] f32 = 2 MB
  if (ws_size < 70352896) return;

  hipFuncSetAttribute((const void*)k_gemm_cell,
                      hipFuncAttributeMaxDynamicSharedMemorySize, 135168);

  k_prep_big<<<4096, 256, 0, stream>>>(fw_Whh0, fw_Wih1, fw_Whh1, bw_Whh0, bw_Wih1, bw_Whh1, wbig);
  k_prep_small<<<2176, 256, 0, stream>>>(fw_Wih0, bw_Wih0, fw_bih0, fw_bhh0, fw_bih1, fw_bhh1,
                                         bw_bih0, bw_bhh0, bw_bih1, bw_bhh1, out_W,
                                         wih0p, biasb, owbf);
  k_init<<<4096, 256, 0, stream>>>(fw_bih1, fw_bhh1, bw_bih1, bw_bhh1, c0, c1, h0bf, h1bf);
  hipMemsetAsync(partial, 0, 2097152, stream);
  k_cc0<<<dim3(128, 2), 256, 0, stream>>>(h1bf, h1bf + (size_t)2 * 524288, out_W, partial);

  for (int t = 0; t < NT; ++t) {
    int p = t & 1;

    GArgs a0;
    for (int d = 0; d < 2; ++d) {
      a0.A0[d] = h0bf + (size_t)(d * 2 + p) * 524288;
      a0.W0[d] = wbig + (size_t)(d * 3 + 0) * 4194304;
      a0.A1[d] = a0.A0[d]; a0.W1[d] = a0.W0[d];   // unused
      a0.Wcc[d] = wih0p + (size_t)d * 262144;
      a0.bias[d] = biasb + (d * 2 + 0) * 4096;
      a0.c_st[d] = c0 + (size_t)d * 524288;
      a0.h_out[d] = h0bf + (size_t)(d * 2 + (1 - p)) * 524288;
    }
    a0.ccpart_in = partial; a0.ccpart_out = nullptr;
    a0.values = values; a0.masks = masks; a0.outb = out_b; a0.owbf = nullptr;
    a0.nk = 17; a0.nk0 = 16; a0.ccmode = 1; a0.t = t;
    k_gemm_cell<<<dim3(32, 4, 2), 256, 135168, stream>>>(a0);

    GArgs a1;
    for (int d = 0; d < 2; ++d) {
      a1.A0[d] = h0bf + (size_t)(d * 2 + (1 - p)) * 524288;
      a1.W0[d] = wbig + (size_t)(d * 3 + 1) * 4194304;
      a1.A1[d] = h1bf + (size_t)(d * 2 + p) * 524288;
      a1.W1[d] = wbig + (size_t)(d * 3 + 2) * 4194304;
      a1.Wcc[d] = a1.W0[d];  // unused
      a1.bias[d] = biasb + (d * 2 + 1) * 4096;
      a1.c_st[d] = c1 + (size_t)d * 524288;
      a1.h_out[d] = h1bf + (size_t)(d * 2 + (1 - p)) * 524288;
    }
    a1.ccpart_in = nullptr; a1.ccpart_out = partial;
    a1.values = values; a1.masks = masks; a1.outb = out_b; a1.owbf = owbf;
    a1.nk = 32; a1.nk0 = 16; a1.ccmode = 0; a1.t = t;
    k_gemm_cell<<<dim3(32, 4, 2), 256, 135168, stream>>>(a1);
  }

  // after t=63: p=1, final h1 in buffer (1-p)=0
  k_final<<<2048, 256, 0, stream>>>(h1bf, h1bf + (size_t)2 * 524288, values, masks, (float*)d_out);
}